// Round 4
// baseline (724.496 us; speedup 1.0000x reference)
//
#include <hip/hip_runtime.h>
#include <hip/hip_fp16.h>

#define HASH_PRIME 5099
#define NE 64
#define ND 512
#define NF 1792
#define NS 32768
#define CAP 512

typedef unsigned short u16;
typedef __attribute__((ext_vector_type(8))) short bf16x8;
typedef __attribute__((ext_vector_type(4))) float f32x4;

__device__ __forceinline__ u16 f2bf(float f) {
  union { float f; unsigned u; } v; v.f = f;
  return (u16)((v.u + 0x7FFFu + ((v.u >> 16) & 1u)) >> 16);
}
__device__ __forceinline__ unsigned pkbf2(float a, float b) {
  return (unsigned)f2bf(a) | ((unsigned)f2bf(b) << 16);
}

// async global->LDS, 16B per lane. LDS dest is wave-uniform base + lane*16.
__device__ __forceinline__ void gld16(const void* g, void* l) {
  __builtin_amdgcn_global_load_lds(
      (const __attribute__((address_space(1))) unsigned int*)(uintptr_t)g,
      (__attribute__((address_space(3))) unsigned int*)(uintptr_t)l,
      16, 0, 0);
}

// ---------------- routing ----------------
__global__ __launch_bounds__(512) void route1(const int* __restrict__ tok,
                                              int* __restrict__ rank_local,
                                              int* __restrict__ hist) {
  __shared__ int se[512];
  __shared__ int h[NE];
  int b = blockIdx.x, t = threadIdx.x;
  int s = b * 512 + t;
  int e = (tok[s] % HASH_PRIME) % NE;
  se[t] = e;
  if (t < NE) h[t] = 0;
  __syncthreads();
  int cnt = 0;
  for (int j = 0; j < t; ++j) cnt += (se[j] == e);
  rank_local[s] = cnt;
  atomicAdd(&h[e], 1);
  __syncthreads();
  if (t < NE) hist[b * NE + t] = h[t];
}

__global__ __launch_bounds__(512) void route2(const int* __restrict__ tok,
                                              const int* __restrict__ rank_local,
                                              const int* __restrict__ hist,
                                              int* __restrict__ slot_src) {
  __shared__ int off[NE];
  int b = blockIdx.x, t = threadIdx.x;
  if (t < NE) {
    int o = 0;
    for (int bb = 0; bb < b; ++bb) o += hist[bb * NE + t];
    off[t] = o;
  }
  __syncthreads();
  int s = b * 512 + t;
  int e = (tok[s] % HASH_PRIME) % NE;
  int pos = off[e] + rank_local[s];
  if (pos < CAP) slot_src[e * CAP + pos] = s;
}

// ---------------- dispatch: gather X -> bf16 Xd[E,CAP,D], zero dropped ----------------
__global__ __launch_bounds__(256) void dispatchx(const float* __restrict__ x,
                                                 const int* __restrict__ slot_src,
                                                 u16* __restrict__ Xd) {
  int b = blockIdx.x;           // 8192 blocks, 4 rows each
  int t = threadIdx.x;
  int row = b * 4 + (t >> 6);   // e*CAP + c
  int col = (t & 63) * 8;
  int s = slot_src[row];
  uint4 w = make_uint4(0u, 0u, 0u, 0u);
  if (s >= 0) {
    const float4* p = (const float4*)(x + (size_t)s * ND + col);
    float4 a = p[0], c = p[1];
    w.x = pkbf2(a.x, a.y); w.y = pkbf2(a.z, a.w);
    w.z = pkbf2(c.x, c.y); w.w = pkbf2(c.z, c.w);
  }
  *(uint4*)(Xd + (size_t)row * ND + col) = w;
}

// ---------------- GEMM machinery ----------------
// 256x128 tile, BK=32, 512 threads = 8 waves (4m x 2n), each wave 64x64 via
// 4x4 mfma_f32_16x16x32_bf16.
// LDS layout: halfword idx = r*32 + ((kb ^ (r&3))*8) + j  (kb = k/8 slot).
// XOR swizzle spreads the 16B slots of rows across bank groups:
//   ds_read_b128 fragment reads (lanes = consecutive r, fixed kb) -> <=2-way (free)
//   B ds_write (4 lanes same row, kb=0..3) -> 4 distinct bank groups, conflict-free
// A staged via global_load_lds with PRE-SWIZZLED per-lane global source
// (permutation within each 64B row segment -> coalescing preserved, rule 21).

#define GDECL \
  __shared__ u16 As[2][256 * 32]; \
  __shared__ u16 Bs[2][128 * 32]; \
  const int t = threadIdx.x; \
  const int l = t & 63; \
  const int w = t >> 6; \
  const int wm = w >> 1; \
  const int wn = w & 1; \
  const int lrow = l & 15; \
  const int swz = ((l >> 4) ^ (l & 3)) * 8; \
  const int ra_row = t >> 2; \
  const int ra_col = (((t & 3) ^ (ra_row & 3)) * 8); \
  const int brow = t >> 2; \
  const int bseg = t & 3; \
  const int wb_idx = brow * 32 + (((bseg ^ (brow & 3)) * 8));

#define INIT_ACC do { \
  _Pragma("unroll") for (int m_ = 0; m_ < 4; ++m_) \
    _Pragma("unroll") for (int n_ = 0; n_ < 4; ++n_) \
      acc[m_][n_] = (f32x4){0.f, 0.f, 0.f, 0.f}; \
} while (0)

#define ISSUE_A(buf, ks, abase, astride) do { \
  const u16* g_ = (abase) + (size_t)ra_row * (astride) + (ks) * 32 + ra_col; \
  gld16(g_, (char*)As[buf] + t * 16); \
  gld16(g_ + (size_t)128 * (astride), (char*)As[buf] + t * 16 + 8192); \
} while (0)

#define LOAD_B(ks, bbase, bstride) do { \
  const float4* p_ = (const float4*)((bbase) + (size_t)brow * (bstride) + (ks) * 32 + bseg * 8); \
  fb0 = p_[0]; fb1 = p_[1]; \
} while (0)

#define WRITE_B(buf) do { \
  uint4 wv_; \
  wv_.x = pkbf2(fb0.x, fb0.y); wv_.y = pkbf2(fb0.z, fb0.w); \
  wv_.z = pkbf2(fb1.x, fb1.y); wv_.w = pkbf2(fb1.z, fb1.w); \
  *(uint4*)&Bs[buf][wb_idx] = wv_; \
} while (0)

#define COMPUTE(buf) do { \
  bf16x8 af_[4], bf_[4]; \
  _Pragma("unroll") for (int m_ = 0; m_ < 4; ++m_) \
    af_[m_] = *(const bf16x8*)&As[buf][(wm * 64 + m_ * 16 + lrow) * 32 + swz]; \
  _Pragma("unroll") for (int n_ = 0; n_ < 4; ++n_) \
    bf_[n_] = *(const bf16x8*)&Bs[buf][(wn * 64 + n_ * 16 + lrow) * 32 + swz]; \
  _Pragma("unroll") for (int m_ = 0; m_ < 4; ++m_) \
    _Pragma("unroll") for (int n_ = 0; n_ < 4; ++n_) \
      acc[m_][n_] = __builtin_amdgcn_mfma_f32_16x16x32_bf16(af_[m_], bf_[n_], acc[m_][n_], 0, 0, 0); \
} while (0)

#define GEMM_LOOP(NK, abase, astride, bbase, bstride) do { \
  float4 fb0, fb1; \
  ISSUE_A(0, 0, abase, astride); \
  LOAD_B(0, bbase, bstride); \
  WRITE_B(0); \
  __syncthreads(); \
  _Pragma("unroll 2") \
  for (int ks = 0; ks < (NK); ++ks) { \
    const int cur = ks & 1; \
    if (ks + 1 < (NK)) { \
      ISSUE_A(cur ^ 1, ks + 1, abase, astride); \
      LOAD_B(ks + 1, bbase, bstride); \
    } \
    COMPUTE(cur); \
    if (ks + 1 < (NK)) WRITE_B(cur ^ 1); \
    __syncthreads(); \
  } \
} while (0)

// ---------------- G1: H = relu(Xd Wk^T)^2, bf16 ----------------
__global__ __launch_bounds__(512, 6) void g1(const u16* __restrict__ Xd,
                                             const float* __restrict__ Wk,
                                             u16* __restrict__ H) {
  GDECL
  // 1792 blocks: bijective XCD swizzle, 8 experts per XCD, m innermost
  const int wg = (blockIdx.x & 7) * (1792 / 8) + (blockIdx.x >> 3);
  const int e = wg / 28, rem = wg % 28;
  const int n0 = (rem >> 1) * 128;
  const int m0 = (rem & 1) * 256;
  f32x4 acc[4][4];
  INIT_ACC;
  const u16*  abase = Xd + ((size_t)e * CAP + m0) * ND;
  const float* bbase = Wk + ((size_t)e * NF + n0) * ND;
  GEMM_LOOP(16, abase, ND, bbase, ND);

  #pragma unroll
  for (int m = 0; m < 4; ++m) {
    #pragma unroll
    for (int i = 0; i < 4; ++i) {
      int r = m0 + wm * 64 + m * 16 + (l >> 4) * 4 + i;
      size_t base = ((size_t)e * CAP + r) * NF + n0 + wn * 64 + lrow;
      #pragma unroll
      for (int n = 0; n < 4; ++n) {
        float v = acc[m][n][i];
        v = v > 0.f ? v * v : 0.f;
        H[base + n * 16] = f2bf(v);
      }
    }
  }
}

// ---------------- G2a: R = sigmoid(Xd Wr^T), fp16 ----------------
__global__ __launch_bounds__(512, 6) void g2a(const u16* __restrict__ Xd,
                                              const float* __restrict__ Wr,
                                              __half* __restrict__ R) {
  GDECL
  // 512 blocks
  const int wg = (blockIdx.x & 7) * (512 / 8) + (blockIdx.x >> 3);
  const int e = wg / 8, rem = wg % 8;
  const int n0 = (rem >> 1) * 128;
  const int m0 = (rem & 1) * 256;
  f32x4 acc[4][4];
  INIT_ACC;
  const u16*  abase = Xd + ((size_t)e * CAP + m0) * ND;
  const float* bbase = Wr + ((size_t)e * ND + n0) * ND;
  GEMM_LOOP(16, abase, ND, bbase, ND);

  #pragma unroll
  for (int m = 0; m < 4; ++m) {
    #pragma unroll
    for (int i = 0; i < 4; ++i) {
      int r = m0 + wm * 64 + m * 16 + (l >> 4) * 4 + i;
      size_t base = ((size_t)e * CAP + r) * ND + n0 + wn * 64 + lrow;
      #pragma unroll
      for (int n = 0; n < 4; ++n) {
        float s = 1.f / (1.f + __expf(-acc[m][n][i]));
        R[base + n * 16] = __float2half(s);
      }
    }
  }
}

// ---------------- G2b: out = R * (H Wv^T), scatter ----------------
__global__ __launch_bounds__(512, 4) void g2b(const u16* __restrict__ H,
                                              const float* __restrict__ Wv,
                                              const __half* __restrict__ R,
                                              const int* __restrict__ slot_src,
                                              float* __restrict__ out) {
  GDECL
  __shared__ int ss[256];
  const int wg = (blockIdx.x & 7) * (512 / 8) + (blockIdx.x >> 3);
  const int e = wg / 8, rem = wg % 8;
  const int n0 = (rem >> 1) * 128;
  const int m0 = (rem & 1) * 256;
  if (t < 256) ss[t] = slot_src[e * CAP + m0 + t];
  f32x4 acc[4][4];
  INIT_ACC;
  const u16*  abase = H  + ((size_t)e * CAP + m0) * NF;
  const float* bbase = Wv + ((size_t)e * ND + n0) * NF;
  GEMM_LOOP(56, abase, NF, bbase, NF);

  #pragma unroll
  for (int m = 0; m < 4; ++m) {
    #pragma unroll
    for (int i = 0; i < 4; ++i) {
      int rl = wm * 64 + m * 16 + (l >> 4) * 4 + i;
      int s = ss[rl];
      if (s >= 0) {
        const __half* rp = R + ((size_t)e * CAP + m0 + rl) * ND + n0 + wn * 64 + lrow;
        float* op = out + (size_t)s * ND + n0 + wn * 64 + lrow;
        #pragma unroll
        for (int n = 0; n < 4; ++n) {
          op[n * 16] = __half2float(rp[n * 16]) * acc[m][n][i];
        }
      }
    }
  }
}

extern "C" void kernel_launch(void* const* d_in, const int* in_sizes, int n_in,
                              void* d_out, int out_size, void* d_ws, size_t ws_size,
                              hipStream_t stream) {
  const float* x   = (const float*)d_in[0];
  const int*   tok = (const int*)d_in[1];
  const float* Wk  = (const float*)d_in[2];
  const float* Wr  = (const float*)d_in[3];
  const float* Wv  = (const float*)d_in[4];
  float* out = (float*)d_out;

  char* ws = (char*)d_ws;
  int*    slot_src   = (int*)ws;                        // 131072 B
  int*    rank_local = (int*)(ws + 131072);             // 131072 B
  int*    hist       = (int*)(ws + 262144);             // 16384 B
  u16*    Xd         = (u16*)(ws + (1 << 20));          // 33.5 MB
  __half* R          = (__half*)(ws + 34603008);        // 33.5 MB
  u16*    H          = (u16*)(ws + 68157440);           // 117.4 MB  (end ~177 MB)

  (void)hipMemsetAsync(d_out, 0, (size_t)out_size * sizeof(float), stream);
  (void)hipMemsetAsync(slot_src, 0xFF, NE * CAP * sizeof(int), stream);
  route1<<<64, 512, 0, stream>>>(tok, rank_local, hist);
  route2<<<64, 512, 0, stream>>>(tok, rank_local, hist, slot_src);
  dispatchx<<<NS / 4, 256, 0, stream>>>(x, slot_src, Xd);
  g1 <<<1792, 512, 0, stream>>>(Xd, Wk, H);
  g2a<<<512,  512, 0, stream>>>(Xd, Wr, R);
  g2b<<<512,  512, 0, stream>>>(H, Wv, R, slot_src, out);
}

// Round 5
// 343.450 us; speedup vs baseline: 2.1095x; 2.1095x over previous
//
#include <hip/hip_runtime.h>
#include <hip/hip_fp16.h>

#define HASH_PRIME 5099
#define NE 64
#define ND 512
#define NF 1792
#define NS 32768
#define CAP 512

typedef unsigned short u16;
typedef __attribute__((ext_vector_type(8))) short bf16x8;
typedef __attribute__((ext_vector_type(4))) float f32x4;

__device__ __forceinline__ u16 f2bf(float f) {
  union { float f; unsigned u; } v; v.f = f;
  return (u16)((v.u + 0x7FFFu + ((v.u >> 16) & 1u)) >> 16);
}
__device__ __forceinline__ unsigned pkbf2(float a, float b) {
  return (unsigned)f2bf(a) | ((unsigned)f2bf(b) << 16);
}

// async global->LDS, 16B per lane. LDS dest is wave-uniform base + lane*16.
__device__ __forceinline__ void gld16(const void* g, void* l) {
  __builtin_amdgcn_global_load_lds(
      (const __attribute__((address_space(1))) unsigned int*)(uintptr_t)g,
      (__attribute__((address_space(3))) unsigned int*)(uintptr_t)l,
      16, 0, 0);
}

// ---------------- routing ----------------
__global__ __launch_bounds__(512) void route1(const int* __restrict__ tok,
                                              int* __restrict__ rank_local,
                                              int* __restrict__ hist) {
  __shared__ int se[512];
  __shared__ int h[NE];
  int b = blockIdx.x, t = threadIdx.x;
  int s = b * 512 + t;
  int e = (tok[s] % HASH_PRIME) % NE;
  se[t] = e;
  if (t < NE) h[t] = 0;
  __syncthreads();
  int cnt = 0;
  for (int j = 0; j < t; ++j) cnt += (se[j] == e);
  rank_local[s] = cnt;
  atomicAdd(&h[e], 1);
  __syncthreads();
  if (t < NE) hist[b * NE + t] = h[t];
}

__global__ __launch_bounds__(512) void route2(const int* __restrict__ tok,
                                              const int* __restrict__ rank_local,
                                              const int* __restrict__ hist,
                                              int* __restrict__ slot_src) {
  __shared__ int off[NE];
  int b = blockIdx.x, t = threadIdx.x;
  if (t < NE) {
    int o = 0;
    for (int bb = 0; bb < b; ++bb) o += hist[bb * NE + t];
    off[t] = o;
  }
  __syncthreads();
  int s = b * 512 + t;
  int e = (tok[s] % HASH_PRIME) % NE;
  int pos = off[e] + rank_local[s];
  if (pos < CAP) slot_src[e * CAP + pos] = s;
}

// ---------------- dispatch: gather X -> bf16 Xd[E,CAP,D], zero dropped ----------------
__global__ __launch_bounds__(256) void dispatchx(const float* __restrict__ x,
                                                 const int* __restrict__ slot_src,
                                                 u16* __restrict__ Xd) {
  int b = blockIdx.x;           // 8192 blocks, 4 rows each
  int t = threadIdx.x;
  int row = b * 4 + (t >> 6);   // e*CAP + c
  int col = (t & 63) * 8;
  int s = slot_src[row];
  uint4 w = make_uint4(0u, 0u, 0u, 0u);
  if (s >= 0) {
    const float4* p = (const float4*)(x + (size_t)s * ND + col);
    float4 a = p[0], c = p[1];
    w.x = pkbf2(a.x, a.y); w.y = pkbf2(a.z, a.w);
    w.z = pkbf2(c.x, c.y); w.w = pkbf2(c.z, c.w);
  }
  *(uint4*)(Xd + (size_t)row * ND + col) = w;
}

// ---------------- GEMM machinery ----------------
// 256x128 tile, BK=32, 512 threads = 8 waves (4m x 2n), each wave 64x64 via
// 4x4 mfma_f32_16x16x32_bf16.
// LDS layout: halfword idx = r*32 + ((kb ^ ((r>>1)&3))*8) + j.
// Bank math for fragment reads (16-lane phase, fixed kb, rows r=0..15):
//   byte addr = r*64 + (kb^((r>>1)&3))*16 -> bank-pos (r*16 + slot*4) mod 32
//   hits {0,16,4,20,8,24,12,28} exactly twice -> 2-way = free (m136).
// B ds_write: rows 0-3 x 4 permuted slots cover 256B -> each bank 2x, free.
// A staged via global_load_lds with PRE-SWIZZLED per-lane global source
// (same involution on source and read, linear LDS dest — rule 21).

#define GDECL \
  __shared__ u16 As[2][256 * 32]; \
  __shared__ u16 Bs[2][128 * 32]; \
  const int t = threadIdx.x; \
  const int l = t & 63; \
  const int w = t >> 6; \
  const int wm = w >> 1; \
  const int wn = w & 1; \
  const int lrow = l & 15; \
  const int swz = ((l >> 4) ^ ((l >> 1) & 3)) * 8; \
  const int ra_row = t >> 2; \
  const int ra_col = ((t & 3) ^ ((t >> 3) & 3)) * 8; \
  const int brow = t >> 2; \
  const int bseg = t & 3; \
  const int wb_idx = brow * 32 + (((t & 3) ^ ((t >> 3) & 3)) * 8);

#define INIT_ACC do { \
  _Pragma("unroll") for (int m_ = 0; m_ < 4; ++m_) \
    _Pragma("unroll") for (int n_ = 0; n_ < 4; ++n_) \
      acc[m_][n_] = (f32x4){0.f, 0.f, 0.f, 0.f}; \
} while (0)

#define ISSUE_A(buf, ks, abase, astride) do { \
  const u16* g_ = (abase) + (size_t)ra_row * (astride) + (ks) * 32 + ra_col; \
  gld16(g_, (char*)As[buf] + t * 16); \
  gld16(g_ + (size_t)128 * (astride), (char*)As[buf] + t * 16 + 8192); \
} while (0)

#define LOAD_B(ks, bbase, bstride) do { \
  const float4* p_ = (const float4*)((bbase) + (size_t)brow * (bstride) + (ks) * 32 + bseg * 8); \
  fb0 = p_[0]; fb1 = p_[1]; \
} while (0)

#define WRITE_B(buf) do { \
  uint4 wv_; \
  wv_.x = pkbf2(fb0.x, fb0.y); wv_.y = pkbf2(fb0.z, fb0.w); \
  wv_.z = pkbf2(fb1.x, fb1.y); wv_.w = pkbf2(fb1.z, fb1.w); \
  *(uint4*)&Bs[buf][wb_idx] = wv_; \
} while (0)

#define COMPUTE(buf) do { \
  bf16x8 af_[4], bf_[4]; \
  _Pragma("unroll") for (int m_ = 0; m_ < 4; ++m_) \
    af_[m_] = *(const bf16x8*)&As[buf][(wm * 64 + m_ * 16 + lrow) * 32 + swz]; \
  _Pragma("unroll") for (int n_ = 0; n_ < 4; ++n_) \
    bf_[n_] = *(const bf16x8*)&Bs[buf][(wn * 64 + n_ * 16 + lrow) * 32 + swz]; \
  _Pragma("unroll") for (int m_ = 0; m_ < 4; ++m_) \
    _Pragma("unroll") for (int n_ = 0; n_ < 4; ++n_) \
      acc[m_][n_] = __builtin_amdgcn_mfma_f32_16x16x32_bf16(af_[m_], bf_[n_], acc[m_][n_], 0, 0, 0); \
} while (0)

#define GEMM_LOOP(NK, abase, astride, bbase, bstride) do { \
  float4 fb0, fb1; \
  ISSUE_A(0, 0, abase, astride); \
  LOAD_B(0, bbase, bstride); \
  WRITE_B(0); \
  __syncthreads(); \
  _Pragma("unroll 2") \
  for (int ks = 0; ks < (NK); ++ks) { \
    const int cur = ks & 1; \
    if (ks + 1 < (NK)) { \
      ISSUE_A(cur ^ 1, ks + 1, abase, astride); \
      LOAD_B(ks + 1, bbase, bstride); \
    } \
    COMPUTE(cur); \
    if (ks + 1 < (NK)) WRITE_B(cur ^ 1); \
    __syncthreads(); \
  } \
} while (0)

// ---------------- G1: H = relu(Xd Wk^T)^2, bf16 ----------------
__global__ __launch_bounds__(512, 4) void g1(const u16* __restrict__ Xd,
                                             const float* __restrict__ Wk,
                                             u16* __restrict__ H) {
  GDECL
  // 1792 blocks: bijective XCD swizzle, 8 experts per XCD, m innermost
  const int wg = (blockIdx.x & 7) * (1792 / 8) + (blockIdx.x >> 3);
  const int e = wg / 28, rem = wg % 28;
  const int n0 = (rem >> 1) * 128;
  const int m0 = (rem & 1) * 256;
  f32x4 acc[4][4];
  INIT_ACC;
  const u16*  abase = Xd + ((size_t)e * CAP + m0) * ND;
  const float* bbase = Wk + ((size_t)e * NF + n0) * ND;
  GEMM_LOOP(16, abase, ND, bbase, ND);

  #pragma unroll
  for (int m = 0; m < 4; ++m) {
    #pragma unroll
    for (int i = 0; i < 4; ++i) {
      int r = m0 + wm * 64 + m * 16 + (l >> 4) * 4 + i;
      size_t base = ((size_t)e * CAP + r) * NF + n0 + wn * 64 + lrow;
      #pragma unroll
      for (int n = 0; n < 4; ++n) {
        float v = acc[m][n][i];
        v = v > 0.f ? v * v : 0.f;
        H[base + n * 16] = f2bf(v);
      }
    }
  }
}

// ---------------- G2a: R = sigmoid(Xd Wr^T), fp16 ----------------
__global__ __launch_bounds__(512, 4) void g2a(const u16* __restrict__ Xd,
                                              const float* __restrict__ Wr,
                                              __half* __restrict__ R) {
  GDECL
  // 512 blocks
  const int wg = (blockIdx.x & 7) * (512 / 8) + (blockIdx.x >> 3);
  const int e = wg / 8, rem = wg % 8;
  const int n0 = (rem >> 1) * 128;
  const int m0 = (rem & 1) * 256;
  f32x4 acc[4][4];
  INIT_ACC;
  const u16*  abase = Xd + ((size_t)e * CAP + m0) * ND;
  const float* bbase = Wr + ((size_t)e * ND + n0) * ND;
  GEMM_LOOP(16, abase, ND, bbase, ND);

  #pragma unroll
  for (int m = 0; m < 4; ++m) {
    #pragma unroll
    for (int i = 0; i < 4; ++i) {
      int r = m0 + wm * 64 + m * 16 + (l >> 4) * 4 + i;
      size_t base = ((size_t)e * CAP + r) * ND + n0 + wn * 64 + lrow;
      #pragma unroll
      for (int n = 0; n < 4; ++n) {
        float s = 1.f / (1.f + __expf(-acc[m][n][i]));
        R[base + n * 16] = __float2half(s);
      }
    }
  }
}

// ---------------- G2b: out = R * (H Wv^T), scatter ----------------
__global__ __launch_bounds__(512, 4) void g2b(const u16* __restrict__ H,
                                              const float* __restrict__ Wv,
                                              const __half* __restrict__ R,
                                              const int* __restrict__ slot_src,
                                              float* __restrict__ out) {
  GDECL
  __shared__ int ss[256];
  const int wg = (blockIdx.x & 7) * (512 / 8) + (blockIdx.x >> 3);
  const int e = wg / 8, rem = wg % 8;
  const int n0 = (rem >> 1) * 128;
  const int m0 = (rem & 1) * 256;
  if (t < 256) ss[t] = slot_src[e * CAP + m0 + t];
  f32x4 acc[4][4];
  INIT_ACC;
  const u16*  abase = H  + ((size_t)e * CAP + m0) * NF;
  const float* bbase = Wv + ((size_t)e * ND + n0) * NF;
  GEMM_LOOP(56, abase, NF, bbase, NF);

  #pragma unroll
  for (int m = 0; m < 4; ++m) {
    #pragma unroll
    for (int i = 0; i < 4; ++i) {
      int rl = wm * 64 + m * 16 + (l >> 4) * 4 + i;
      int s = ss[rl];
      if (s >= 0) {
        const __half* rp = R + ((size_t)e * CAP + m0 + rl) * ND + n0 + wn * 64 + lrow;
        float* op = out + (size_t)s * ND + n0 + wn * 64 + lrow;
        #pragma unroll
        for (int n = 0; n < 4; ++n) {
          op[n * 16] = __half2float(rp[n * 16]) * acc[m][n][i];
        }
      }
    }
  }
}

extern "C" void kernel_launch(void* const* d_in, const int* in_sizes, int n_in,
                              void* d_out, int out_size, void* d_ws, size_t ws_size,
                              hipStream_t stream) {
  const float* x   = (const float*)d_in[0];
  const int*   tok = (const int*)d_in[1];
  const float* Wk  = (const float*)d_in[2];
  const float* Wr  = (const float*)d_in[3];
  const float* Wv  = (const float*)d_in[4];
  float* out = (float*)d_out;

  char* ws = (char*)d_ws;
  int*    slot_src   = (int*)ws;                        // 131072 B
  int*    rank_local = (int*)(ws + 131072);             // 131072 B
  int*    hist       = (int*)(ws + 262144);             // 16384 B
  u16*    Xd         = (u16*)(ws + (1 << 20));          // 33.5 MB
  __half* R          = (__half*)(ws + 34603008);        // 33.5 MB
  u16*    H          = (u16*)(ws + 68157440);           // 117.4 MB  (end ~177 MB)

  (void)hipMemsetAsync(d_out, 0, (size_t)out_size * sizeof(float), stream);
  (void)hipMemsetAsync(slot_src, 0xFF, NE * CAP * sizeof(int), stream);
  route1<<<64, 512, 0, stream>>>(tok, rank_local, hist);
  route2<<<64, 512, 0, stream>>>(tok, rank_local, hist, slot_src);
  dispatchx<<<NS / 4, 256, 0, stream>>>(x, slot_src, Xd);
  g1 <<<1792, 512, 0, stream>>>(Xd, Wk, H);
  g2a<<<512,  512, 0, stream>>>(Xd, Wr, R);
  g2b<<<512,  512, 0, stream>>>(H, Wv, R, slot_src, out);
}